// Round 5
// baseline (14.078 us; speedup 1.0000x reference)
//
#include <hip/hip_runtime.h>
#include <math.h>

// MorphLayer via max-product identity (exp monotone, exp∘log∘clamp = clamp):
//   exp(max_k(log(max(±x,eps)) + w_k)) = max_k( max(±x,eps) * exp(w_k) )
// Negation identity: max(-v,e)*w = max(-(v*w), e*w); e*w ~ 1e-12 -> init 0.
// k processed in pairs -> fmaxf(fmaxf(m,a),b) fuses to v_max3_f32.
// 2 output rows per thread -> weight LDS reads amortized 2x.

#define BB 16
#define CC 3
#define HH 66
#define WW 66
#define HO 64
#define WO 64
#define FF 32
#define KK 27
#define FPG 4               // filters per block
#define FG (FF / FPG)       // 8 filter groups
#define ROWS 8              // output rows per block (2 per thread)
#define IR (ROWS + 2)       // staged input rows = 10

typedef float f32x2 __attribute__((ext_vector_type(2)));

__global__ __launch_bounds__(256, 4)
void morph_fused(const float* __restrict__ x,
                 const float* __restrict__ k1,
                 const float* __restrict__ k2,
                 const float* __restrict__ bias,
                 float* __restrict__ out) {
    __shared__ float xs[CC * IR * WW];   // raw x window, 7920 B
    __shared__ float wl[KK * 8];         // [k][e1 x4 | e2 x4], 864 B

    const int tid = threadIdx.x;
    int bid = blockIdx.x;
    const int fg = bid & (FG - 1); bid >>= 3;  // filter group 0..7
    const int rg = bid & 7;        bid >>= 3;  // row group 0..7
    const int b  = bid;                        // batch
    const int f0 = fg * FPG;
    const int ho0 = rg * ROWS;

    // ---- stage exp(weights) for this block's 4 filters ----
    if (tid < KK * 8) {
        const int k = tid >> 3;
        const int j = tid & 3;
        const int h = (tid >> 2) & 1;
        const float w = h ? k2[k * FF + f0 + j] : k1[k * FF + f0 + j];
        wl[tid] = expf(w);
    }
    // ---- stage raw x window ----
    const float* xb = x + (size_t)b * CC * HH * WW;
    for (int i = tid; i < CC * IR * WW; i += 256) {
        const int c   = i / (IR * WW);
        const int rem = i - c * (IR * WW);
        const int row = rem / WW;
        const int col = rem - row * WW;
        xs[i] = xb[(c * HH + ho0 + row) * WW + col];
    }
    __syncthreads();

    const int wo = tid & 63;
    const int r  = tid >> 6;   // 0..3; thread owns rows r and r+4

    // 32 accumulator chains: [row-half][filter]
    float m11[2][4], m12[2][4], m21[2][4], m22[2][4];
    #pragma unroll
    for (int h = 0; h < 2; ++h)
        #pragma unroll
        for (int j = 0; j < 4; ++j) {
            m11[h][j] = 0.f; m12[h][j] = 0.f; m21[h][j] = 0.f; m22[h][j] = 0.f;
        }

    const f32x2* wl2 = (const f32x2*)wl;

    // x index for compile-time k, runtime row-half h
#define XIDX(h, k) \
    ((((k) / 9) * IR + r + 4 * (h) + (((k) % 9) / 3)) * WW + wo + ((k) % 3))

    // one k-pair, one row-half: 8 pk_mul + 16 max3
#define PAIR_H(h, ka, kb) { \
        const float va = xs[XIDX(h, ka)]; \
        const float vb = xs[XIDX(h, kb)]; \
        const f32x2 va2 = {va, va}, vb2 = {vb, vb}; \
        f32x2 pa0 = va2 * wl2[(ka)*4+0], pa1 = va2 * wl2[(ka)*4+1]; \
        f32x2 pa2 = va2 * wl2[(ka)*4+2], pa3 = va2 * wl2[(ka)*4+3]; \
        f32x2 pb0 = vb2 * wl2[(kb)*4+0], pb1 = vb2 * wl2[(kb)*4+1]; \
        f32x2 pb2 = vb2 * wl2[(kb)*4+2], pb3 = vb2 * wl2[(kb)*4+3]; \
        m11[h][0] = fmaxf(fmaxf(m11[h][0],  pa0.x),  pb0.x); \
        m11[h][1] = fmaxf(fmaxf(m11[h][1],  pa0.y),  pb0.y); \
        m11[h][2] = fmaxf(fmaxf(m11[h][2],  pa1.x),  pb1.x); \
        m11[h][3] = fmaxf(fmaxf(m11[h][3],  pa1.y),  pb1.y); \
        m12[h][0] = fmaxf(fmaxf(m12[h][0],  pa2.x),  pb2.x); \
        m12[h][1] = fmaxf(fmaxf(m12[h][1],  pa2.y),  pb2.y); \
        m12[h][2] = fmaxf(fmaxf(m12[h][2],  pa3.x),  pb3.x); \
        m12[h][3] = fmaxf(fmaxf(m12[h][3],  pa3.y),  pb3.y); \
        m21[h][0] = fmaxf(fmaxf(m21[h][0], -pa0.x), -pb0.x); \
        m21[h][1] = fmaxf(fmaxf(m21[h][1], -pa0.y), -pb0.y); \
        m21[h][2] = fmaxf(fmaxf(m21[h][2], -pa1.x), -pb1.x); \
        m21[h][3] = fmaxf(fmaxf(m21[h][3], -pa1.y), -pb1.y); \
        m22[h][0] = fmaxf(fmaxf(m22[h][0], -pa2.x), -pb2.x); \
        m22[h][1] = fmaxf(fmaxf(m22[h][1], -pa2.y), -pb2.y); \
        m22[h][2] = fmaxf(fmaxf(m22[h][2], -pa3.x), -pb3.x); \
        m22[h][3] = fmaxf(fmaxf(m22[h][3], -pa3.y), -pb3.y); \
    }

    #pragma unroll
    for (int kp = 0; kp < 13; ++kp) {
        PAIR_H(0, 2 * kp, 2 * kp + 1)
        PAIR_H(1, 2 * kp, 2 * kp + 1)
    }
    // tail k = 26
    #pragma unroll
    for (int h = 0; h < 2; ++h) {
        const float va = xs[XIDX(h, 26)];
        const f32x2 va2 = {va, va};
        f32x2 p0 = va2 * wl2[26*4+0], p1 = va2 * wl2[26*4+1];
        f32x2 p2 = va2 * wl2[26*4+2], p3 = va2 * wl2[26*4+3];
        m11[h][0] = fmaxf(m11[h][0],  p0.x); m11[h][1] = fmaxf(m11[h][1],  p0.y);
        m11[h][2] = fmaxf(m11[h][2],  p1.x); m11[h][3] = fmaxf(m11[h][3],  p1.y);
        m12[h][0] = fmaxf(m12[h][0],  p2.x); m12[h][1] = fmaxf(m12[h][1],  p2.y);
        m12[h][2] = fmaxf(m12[h][2],  p3.x); m12[h][3] = fmaxf(m12[h][3],  p3.y);
        m21[h][0] = fmaxf(m21[h][0], -p0.x); m21[h][1] = fmaxf(m21[h][1], -p0.y);
        m21[h][2] = fmaxf(m21[h][2], -p1.x); m21[h][3] = fmaxf(m21[h][3], -p1.y);
        m22[h][0] = fmaxf(m22[h][0], -p2.x); m22[h][1] = fmaxf(m22[h][1], -p2.y);
        m22[h][2] = fmaxf(m22[h][2], -p3.x); m22[h][3] = fmaxf(m22[h][3], -p3.y);
    }
#undef PAIR_H
#undef XIDX

    #pragma unroll
    for (int h = 0; h < 2; ++h) {
        const int ho = ho0 + r + 4 * h;
        #pragma unroll
        for (int j = 0; j < 4; ++j) {
            const float res = m11[h][j] - m12[h][j] - m21[h][j] + m22[h][j]
                            + bias[f0 + j];
            out[(((size_t)b * FF + f0 + j) * HO + ho) * WO + wo] = res;
        }
    }
}

extern "C" void kernel_launch(void* const* d_in, const int* in_sizes, int n_in,
                              void* d_out, int out_size, void* d_ws, size_t ws_size,
                              hipStream_t stream) {
    const float* x    = (const float*)d_in[0];
    const float* k1   = (const float*)d_in[1];
    const float* k2   = (const float*)d_in[2];
    const float* bias = (const float*)d_in[3];
    float* out = (float*)d_out;

    const int nblocks = BB * (HO / ROWS) * FG;  // 16 * 8 * 8 = 1024
    morph_fused<<<dim3(nblocks), dim3(256), 0, stream>>>(x, k1, k2, bias, out);
}

// Round 6
// 13.903 us; speedup vs baseline: 1.0126x; 1.0126x over previous
//
#include <hip/hip_runtime.h>
#include <math.h>

// MorphLayer via max-product identity (exp monotone, exp∘log∘clamp = clamp):
//   exp(max_k(log(max(±x,eps)) + w_k)) = max_k( max(±x,eps) * exp(w_k) )
// Negation identity: max(-v,e)*w = max(-(v*w), e*w); e*w ~ 1e-12 -> init 0.
// k in pairs -> fmaxf(fmaxf(m,a),b) fuses to v_max3_f32 (2 max/issue).
// Weights packed [k][e1 x4 | e2 x4] -> two ds_read_b128 per k (wave-uniform).
// 1 row/thread, 2048 blocks, 8 waves/SIMD for latency hiding.

#define BB 16
#define CC 3
#define HH 66
#define WW 66
#define HO 64
#define WO 64
#define FF 32
#define KK 27
#define FPG 4               // filters per block
#define FG (FF / FPG)       // 8 filter groups
#define ROWS 4              // output rows per block (1 per thread)
#define IR (ROWS + 2)       // staged input rows = 6

typedef float f32x2 __attribute__((ext_vector_type(2)));

__global__ __launch_bounds__(256, 8)
void morph_fused(const float* __restrict__ x,
                 const float* __restrict__ k1,
                 const float* __restrict__ k2,
                 const float* __restrict__ bias,
                 float* __restrict__ out) {
    __shared__ __align__(16) float xs[CC * IR * WW];  // 4752 B
    __shared__ __align__(16) float wl[KK * 8];        // [k][e1 x4 | e2 x4], 864 B

    const int tid = threadIdx.x;
    int bid = blockIdx.x;
    const int fg = bid & (FG - 1); bid >>= 3;  // filter group 0..7
    const int rg = bid & 15;       bid >>= 4;  // row group 0..15
    const int b  = bid;                        // batch
    const int f0 = fg * FPG;
    const int ho0 = rg * ROWS;

    // ---- stage exp(weights): [k][e1x4|e2x4] ----
    if (tid < KK * 8) {
        const int k = tid >> 3;
        const int j = tid & 3;
        const int h = (tid >> 2) & 1;
        const float w = h ? k2[k * FF + f0 + j] : k1[k * FF + f0 + j];
        wl[tid] = expf(w);
    }
    // ---- stage raw x window ----
    const float* xb = x + (size_t)b * CC * HH * WW;
    for (int i = tid; i < CC * IR * WW; i += 256) {
        const int c   = i / (IR * WW);
        const int rem = i - c * (IR * WW);
        const int row = rem / WW;
        const int col = rem - row * WW;
        xs[i] = xb[(c * HH + ho0 + row) * WW + col];
    }
    __syncthreads();

    const int wo = tid & 63;
    const int r  = tid >> 6;   // 0..3, one output row per thread
    const int ho = ho0 + r;

    float m11x = 0.f, m11y = 0.f, m11z = 0.f, m11w = 0.f;
    float m12x = 0.f, m12y = 0.f, m12z = 0.f, m12w = 0.f;
    float m21x = 0.f, m21y = 0.f, m21z = 0.f, m21w = 0.f;
    float m22x = 0.f, m22y = 0.f, m22z = 0.f, m22w = 0.f;

    const float4* wl4 = (const float4*)wl;

#define XIDX(k) \
    ((((k) / 9) * IR + r + (((k) % 9) / 3)) * WW + wo + ((k) % 3))

    // one k-pair: 2 x-reads (b32) + 4 weight reads (b128) + 8 pk_mul + 16 max3
#define PAIR(ka, kb) { \
        const float va = xs[XIDX(ka)]; \
        const float vb = xs[XIDX(kb)]; \
        const float4 w1a = wl4[(ka)*2],   w2a = wl4[(ka)*2+1]; \
        const float4 w1b = wl4[(kb)*2],   w2b = wl4[(kb)*2+1]; \
        const f32x2 va2 = {va, va}, vb2 = {vb, vb}; \
        f32x2 pa0 = va2 * (f32x2){w1a.x, w1a.y}; \
        f32x2 pa1 = va2 * (f32x2){w1a.z, w1a.w}; \
        f32x2 qa0 = va2 * (f32x2){w2a.x, w2a.y}; \
        f32x2 qa1 = va2 * (f32x2){w2a.z, w2a.w}; \
        f32x2 pb0 = vb2 * (f32x2){w1b.x, w1b.y}; \
        f32x2 pb1 = vb2 * (f32x2){w1b.z, w1b.w}; \
        f32x2 qb0 = vb2 * (f32x2){w2b.x, w2b.y}; \
        f32x2 qb1 = vb2 * (f32x2){w2b.z, w2b.w}; \
        m11x = fmaxf(fmaxf(m11x,  pa0.x),  pb0.x); \
        m11y = fmaxf(fmaxf(m11y,  pa0.y),  pb0.y); \
        m11z = fmaxf(fmaxf(m11z,  pa1.x),  pb1.x); \
        m11w = fmaxf(fmaxf(m11w,  pa1.y),  pb1.y); \
        m12x = fmaxf(fmaxf(m12x,  qa0.x),  qb0.x); \
        m12y = fmaxf(fmaxf(m12y,  qa0.y),  qb0.y); \
        m12z = fmaxf(fmaxf(m12z,  qa1.x),  qb1.x); \
        m12w = fmaxf(fmaxf(m12w,  qa1.y),  qb1.y); \
        m21x = fmaxf(fmaxf(m21x, -pa0.x), -pb0.x); \
        m21y = fmaxf(fmaxf(m21y, -pa0.y), -pb0.y); \
        m21z = fmaxf(fmaxf(m21z, -pa1.x), -pb1.x); \
        m21w = fmaxf(fmaxf(m21w, -pa1.y), -pb1.y); \
        m22x = fmaxf(fmaxf(m22x, -qa0.x), -qb0.x); \
        m22y = fmaxf(fmaxf(m22y, -qa0.y), -qb0.y); \
        m22z = fmaxf(fmaxf(m22z, -qa1.x), -qb1.x); \
        m22w = fmaxf(fmaxf(m22w, -qa1.y), -qb1.y); \
    }

    PAIR(0, 1)   PAIR(2, 3)   PAIR(4, 5)   PAIR(6, 7)
    PAIR(8, 9)   PAIR(10, 11) PAIR(12, 13) PAIR(14, 15)
    PAIR(16, 17) PAIR(18, 19) PAIR(20, 21) PAIR(22, 23)
    PAIR(24, 25)
    {   // tail k = 26
        const float va = xs[XIDX(26)];
        const float4 w1 = wl4[26*2], w2 = wl4[26*2+1];
        const f32x2 va2 = {va, va};
        f32x2 p0 = va2 * (f32x2){w1.x, w1.y};
        f32x2 p1 = va2 * (f32x2){w1.z, w1.w};
        f32x2 q0 = va2 * (f32x2){w2.x, w2.y};
        f32x2 q1 = va2 * (f32x2){w2.z, w2.w};
        m11x = fmaxf(m11x,  p0.x); m11y = fmaxf(m11y,  p0.y);
        m11z = fmaxf(m11z,  p1.x); m11w = fmaxf(m11w,  p1.y);
        m12x = fmaxf(m12x,  q0.x); m12y = fmaxf(m12y,  q0.y);
        m12z = fmaxf(m12z,  q1.x); m12w = fmaxf(m12w,  q1.y);
        m21x = fmaxf(m21x, -p0.x); m21y = fmaxf(m21y, -p0.y);
        m21z = fmaxf(m21z, -p1.x); m21w = fmaxf(m21w, -p1.y);
        m22x = fmaxf(m22x, -q0.x); m22y = fmaxf(m22y, -q0.y);
        m22z = fmaxf(m22z, -q1.x); m22w = fmaxf(m22w, -q1.y);
    }
#undef PAIR
#undef XIDX

    const size_t obase = ((size_t)b * FF + f0) * (HO * WO) + (size_t)ho * WO + wo;
    out[obase + 0 * HO * WO] = m11x - m12x - m21x + m22x + bias[f0 + 0];
    out[obase + 1 * HO * WO] = m11y - m12y - m21y + m22y + bias[f0 + 1];
    out[obase + 2 * HO * WO] = m11z - m12z - m21z + m22z + bias[f0 + 2];
    out[obase + 3 * HO * WO] = m11w - m12w - m21w + m22w + bias[f0 + 3];
}

extern "C" void kernel_launch(void* const* d_in, const int* in_sizes, int n_in,
                              void* d_out, int out_size, void* d_ws, size_t ws_size,
                              hipStream_t stream) {
    const float* x    = (const float*)d_in[0];
    const float* k1   = (const float*)d_in[1];
    const float* k2   = (const float*)d_in[2];
    const float* bias = (const float*)d_in[3];
    float* out = (float*)d_out;

    const int nblocks = BB * (HO / ROWS) * FG;  // 16 * 16 * 8 = 2048
    morph_fused<<<dim3(nblocks), dim3(256), 0, stream>>>(x, k1, k2, bias, out);
}